// Round 3
// baseline (48.515 us; speedup 1.0000x reference)
//
#include <hip/hip_runtime.h>

namespace {

constexpr int OUT_F = 11008;
constexpr int IN_F  = 4096;

typedef int      int4v   __attribute__((ext_vector_type(4)));
typedef float    float4v __attribute__((ext_vector_type(4)));
typedef _Float16 half4v  __attribute__((ext_vector_type(4)));

constexpr int ROWS_PER_WAVE   = 2;
constexpr int WAVES_PER_BLOCK = 4;
constexpr int ROWS_PER_BLOCK  = ROWS_PER_WAVE * WAVES_PER_BLOCK;  // 8
constexpr int K_STEPS         = IN_F / (64 * 4);                  // 16 (4 elems/lane/step)
constexpr int CHUNK           = 4;                                // pipeline depth in steps
constexpr int NCHUNK          = K_STEPS / CHUNK;                  // 4

__global__ __launch_bounds__(256, 4) void qlinear_kernel(
    const float* __restrict__ x,       // [4, IN_F]
    const int*   __restrict__ qw,      // [OUT_F, IN_F] int8 values in int32
    const float* __restrict__ scales,  // [OUT_F]
    const float* __restrict__ bias,    // [OUT_F]
    float*       __restrict__ out)     // [4, OUT_F]
{
    // Stage all of x (4 x 4096) into LDS as f16: 32 KB -> 4 blocks/CU resident.
    __shared__ _Float16 xs[4 * IN_F];

    const int tid = threadIdx.x;
    const float4v* xg = (const float4v*)x;
    half4v* xs4 = (half4v*)xs;
#pragma unroll
    for (int j = 0; j < (4 * IN_F / 4) / 256; ++j) {  // 16 iters x 256 threads
        float4v f = xg[j * 256 + tid];
        half4v h;
        h.x = (_Float16)f.x;
        h.y = (_Float16)f.y;
        h.z = (_Float16)f.z;
        h.w = (_Float16)f.w;
        xs4[j * 256 + tid] = h;
    }
    __syncthreads();

    const int lane = tid & 63;
    const int wid  = tid >> 6;
    const int row0 = blockIdx.x * ROWS_PER_BLOCK + wid * ROWS_PER_WAVE;

    const int4v* wp0 = (const int4v*)(qw + (size_t)row0 * IN_F);
    const int4v* wp1 = (const int4v*)(qw + (size_t)(row0 + 1) * IN_F);

    float acc[ROWS_PER_WAVE][4];
#pragma unroll
    for (int r = 0; r < ROWS_PER_WAVE; ++r)
#pragma unroll
        for (int b = 0; b < 4; ++b)
            acc[r][b] = 0.0f;

    // Register double-buffer: while computing chunk c, chunk c+1's 8 loads
    // (2 rows x 4 steps x 1 KB/wave) are in flight on vmcnt. x reads are
    // LDS (lgkmcnt) so they never force a drain of the weight prefetch queue.
    int4v wa[ROWS_PER_WAVE][CHUNK], wb[ROWS_PER_WAVE][CHUNK];

#pragma unroll
    for (int s = 0; s < CHUNK; ++s) {
        wa[0][s] = wp0[s * 64 + lane];
        wa[1][s] = wp1[s * 64 + lane];
    }

#pragma unroll
    for (int c = 0; c < NCHUNK; ++c) {
        if (c + 1 < NCHUNK) {
#pragma unroll
            for (int s = 0; s < CHUNK; ++s) {
                wb[0][s] = wp0[((c + 1) * CHUNK + s) * 64 + lane];
                wb[1][s] = wp1[((c + 1) * CHUNK + s) * 64 + lane];
            }
        }

#pragma unroll
        for (int s = 0; s < CHUNK; ++s) {
            const int k = c * CHUNK + s;
            float4v xv[4];
#pragma unroll
            for (int b = 0; b < 4; ++b) {
                half4v h = xs4[b * (IN_F / 4) + k * 64 + lane];
                xv[b].x = (float)h.x;
                xv[b].y = (float)h.y;
                xv[b].z = (float)h.z;
                xv[b].w = (float)h.w;
            }

#pragma unroll
            for (int r = 0; r < ROWS_PER_WAVE; ++r) {
                float4v wf;
                wf.x = (float)wa[r][s].x;
                wf.y = (float)wa[r][s].y;
                wf.z = (float)wa[r][s].z;
                wf.w = (float)wa[r][s].w;
#pragma unroll
                for (int b = 0; b < 4; ++b) {
                    acc[r][b] += wf.x * xv[b].x;
                    acc[r][b] += wf.y * xv[b].y;
                    acc[r][b] += wf.z * xv[b].z;
                    acc[r][b] += wf.w * xv[b].w;
                }
            }
        }

        if (c + 1 < NCHUNK) {
#pragma unroll
            for (int s = 0; s < CHUNK; ++s) {
                wa[0][s] = wb[0][s];
                wa[1][s] = wb[1][s];
            }
        }
    }

    // Butterfly reduction across the 64 lanes.
#pragma unroll
    for (int r = 0; r < ROWS_PER_WAVE; ++r)
#pragma unroll
        for (int b = 0; b < 4; ++b) {
            float v = acc[r][b];
#pragma unroll
            for (int m = 32; m >= 1; m >>= 1)
                v += __shfl_xor(v, m, 64);
            acc[r][b] = v;
        }

    if (lane == 0) {
#pragma unroll
        for (int r = 0; r < ROWS_PER_WAVE; ++r) {
            const int row = row0 + r;
            const float s  = scales[row];
            const float bz = bias[row];
#pragma unroll
            for (int b = 0; b < 4; ++b)
                out[(size_t)b * OUT_F + row] = acc[r][b] * s + bz;
        }
    }
}

}  // namespace

extern "C" void kernel_launch(void* const* d_in, const int* in_sizes, int n_in,
                              void* d_out, int out_size, void* d_ws, size_t ws_size,
                              hipStream_t stream) {
    const float* x      = (const float*)d_in[0];
    const int*   qw     = (const int*)d_in[1];
    const float* scales = (const float*)d_in[2];
    const float* bias   = (const float*)d_in[3];
    float*       out    = (float*)d_out;

    const int grid = OUT_F / ROWS_PER_BLOCK;  // 1376
    qlinear_kernel<<<grid, 256, 0, stream>>>(x, qw, scales, bias, out);
}

// Round 4
// 33.857 us; speedup vs baseline: 1.4330x; 1.4330x over previous
//
#include <hip/hip_runtime.h>

namespace {

constexpr int OUT_F = 11008;
constexpr int IN_F  = 4096;

typedef int   int4v   __attribute__((ext_vector_type(4)));
typedef float float4v __attribute__((ext_vector_type(4)));

constexpr int ROWS_PER_WAVE   = 2;
constexpr int WAVES_PER_BLOCK = 4;
constexpr int ROWS_PER_BLOCK  = ROWS_PER_WAVE * WAVES_PER_BLOCK;  // 8
constexpr int SLICE_K         = 1024;                             // K per LDS slice
constexpr int NSLICE          = IN_F / SLICE_K;                   // 4
constexpr int STEPS           = SLICE_K / 256;                    // 4 steps/slice (256 k per step)
constexpr int SLICE_F4        = SLICE_K / 4;                      // 256 float4 per batch row

__global__ __launch_bounds__(256, 4) void qlinear_kernel(
    const float* __restrict__ x,       // [4, IN_F]
    const int*   __restrict__ qw,      // [OUT_F, IN_F] int8 values in int32
    const float* __restrict__ scales,  // [OUT_F]
    const float* __restrict__ bias,    // [OUT_F]
    float*       __restrict__ out)     // [4, OUT_F]
{
    // Ping-pong x staging: 2 buffers x (4 batch x 1024 k) fp32 = 2 x 16 KB.
    // 32 KB LDS -> 4 blocks/CU (16 waves/CU), vs 64 KB monolithic -> 2.
    __shared__ float4v xs[2][4 * SLICE_F4];

    const int tid  = threadIdx.x;
    const int lane = tid & 63;
    const int wid  = tid >> 6;
    const int row0 = blockIdx.x * ROWS_PER_BLOCK + wid * ROWS_PER_WAVE;

    const float4v* xg  = (const float4v*)x;  // [4][IN_F/4]
    const int4v*   wp0 = (const int4v*)(qw + (size_t)row0 * IN_F);
    const int4v*   wp1 = (const int4v*)(qw + (size_t)(row0 + 1) * IN_F);

    float acc[ROWS_PER_WAVE][4];
#pragma unroll
    for (int r = 0; r < ROWS_PER_WAVE; ++r)
#pragma unroll
        for (int b = 0; b < 4; ++b)
            acc[r][b] = 0.0f;

    // Prologue: stage slice 0, prefetch weight chunk 0.
    int4v wa[ROWS_PER_WAVE][STEPS], wb[ROWS_PER_WAVE][STEPS];
    {
        float4v t[4];
#pragma unroll
        for (int j = 0; j < 4; ++j)
            t[j] = xg[j * (IN_F / 4) + tid];           // slice 0
#pragma unroll
        for (int s = 0; s < STEPS; ++s) {
            wa[0][s] = wp0[s * 64 + lane];
            wa[1][s] = wp1[s * 64 + lane];
        }
#pragma unroll
        for (int j = 0; j < 4; ++j)
            xs[0][j * SLICE_F4 + tid] = t[j];
    }
    __syncthreads();

#pragma unroll
    for (int c = 0; c < NSLICE; ++c) {
        // Stage slice c+1 into the other buffer; prefetch weight chunk c+1.
        // x loads are issued BEFORE the weight prefetch so the ds_write's
        // s_waitcnt is a counted vmcnt that leaves the 8 weight loads in
        // flight across this chunk's compute.
        if (c + 1 < NSLICE) {
            float4v t[4];
#pragma unroll
            for (int j = 0; j < 4; ++j)
                t[j] = xg[j * (IN_F / 4) + (c + 1) * SLICE_F4 + tid];
#pragma unroll
            for (int s = 0; s < STEPS; ++s) {
                wb[0][s] = wp0[((c + 1) * STEPS + s) * 64 + lane];
                wb[1][s] = wp1[((c + 1) * STEPS + s) * 64 + lane];
            }
#pragma unroll
            for (int j = 0; j < 4; ++j)
                xs[(c + 1) & 1][j * SLICE_F4 + tid] = t[j];
        }

        // Compute chunk c from wa + xs[c&1].
#pragma unroll
        for (int s = 0; s < STEPS; ++s) {
            float4v xv[4];
#pragma unroll
            for (int b = 0; b < 4; ++b)
                xv[b] = xs[c & 1][b * SLICE_F4 + s * 64 + lane];

#pragma unroll
            for (int r = 0; r < ROWS_PER_WAVE; ++r) {
                float4v wf;
                wf.x = (float)wa[r][s].x;
                wf.y = (float)wa[r][s].y;
                wf.z = (float)wa[r][s].z;
                wf.w = (float)wa[r][s].w;
#pragma unroll
                for (int b = 0; b < 4; ++b) {
                    acc[r][b] += wf.x * xv[b].x;
                    acc[r][b] += wf.y * xv[b].y;
                    acc[r][b] += wf.z * xv[b].z;
                    acc[r][b] += wf.w * xv[b].w;
                }
            }
        }

        if (c + 1 < NSLICE) {
            __syncthreads();  // slice c+1 fully written; buf (c&1) free to reuse
#pragma unroll
            for (int s = 0; s < STEPS; ++s) {
                wa[0][s] = wb[0][s];
                wa[1][s] = wb[1][s];
            }
        }
    }

    // Butterfly reduction across the 64 lanes.
#pragma unroll
    for (int r = 0; r < ROWS_PER_WAVE; ++r)
#pragma unroll
        for (int b = 0; b < 4; ++b) {
            float v = acc[r][b];
#pragma unroll
            for (int m = 32; m >= 1; m >>= 1)
                v += __shfl_xor(v, m, 64);
            acc[r][b] = v;
        }

    if (lane == 0) {
#pragma unroll
        for (int r = 0; r < ROWS_PER_WAVE; ++r) {
            const int row = row0 + r;
            const float s  = scales[row];
            const float bz = bias[row];
#pragma unroll
            for (int b = 0; b < 4; ++b)
                out[(size_t)b * OUT_F + row] = acc[r][b] * s + bz;
        }
    }
}

}  // namespace

extern "C" void kernel_launch(void* const* d_in, const int* in_sizes, int n_in,
                              void* d_out, int out_size, void* d_ws, size_t ws_size,
                              hipStream_t stream) {
    const float* x      = (const float*)d_in[0];
    const int*   qw     = (const int*)d_in[1];
    const float* scales = (const float*)d_in[2];
    const float* bias   = (const float*)d_in[3];
    float*       out    = (float*)d_out;

    const int grid = OUT_F / ROWS_PER_BLOCK;  // 1376
    qlinear_kernel<<<grid, 256, 0, stream>>>(x, qw, scales, bias, out);
}